// Round 3
// baseline (479.852 us; speedup 1.0000x reference)
//
#include <hip/hip_runtime.h>

typedef _Float16 h4 __attribute__((ext_vector_type(4)));
typedef float    f4 __attribute__((ext_vector_type(4)));

#define N_B   128
#define N_IN  1152
#define TPW   2              // tiles per wave per stage
#define NSTG  2              // register-stages per block
#define ICH   (TPW * 4 * NSTG)   // 16 i-tiles per block
#define NCH   (N_IN / ICH)       // 72 chunks
#define BSPL  8
#define BCH   (N_B / BSPL)       // 16 b per block

// workspace: Spart [NCH][N_B][256] f32 = 9.44 MB, then Vsum [N_B*256] f32.
// Total 9.57 MB -- below the 9.70 MB proven safe in round 1.
#define SPART_SZ ((size_t)NCH * N_B * 256 * 4)

// sblk value at (bb, q= t*64+lane):
//   route0 (A-layout): s[o=lane&15, d=(lane>>4)*4+t]  -> q = (d&3)*64+(d>>2)*16+o
//   route  (D-layout): s[o=(lane>>4)*4+t, d=lane&15]  -> q = (o&3)*64+(o>>2)*16+d

// ---------------------------------------------------------------------------
// iter 0: c uniform = 1/16. Partial s for this (chunk, b-split) block.
// ---------------------------------------------------------------------------
__global__ __launch_bounds__(256, 3) void k_route0(const float* __restrict__ x,
                                                   const float* __restrict__ W,
                                                   float* __restrict__ Spart) {
    __shared__ float sblk[BCH * 256];
    const int c = blockIdx.x, spl = blockIdx.y;
    const int b0 = spl * BCH;
    const int tid = threadIdx.x, w = tid >> 6, lane = tid & 63;
    const int lo = lane & 15, hi = lane >> 4;

#pragma unroll
    for (int r = 0; r < BCH; r++) sblk[r * 256 + tid] = 0.f;
    __syncthreads();

    for (int stg = 0; stg < NSTG; stg++) {
        const int ibase = c * ICH + stg * (TPW * 4) + w * TPW;
        f4 wreg[TPW][8];
#pragma unroll
        for (int t3 = 0; t3 < TPW; t3++) {
            const f4* wp = (const f4*)(W + (size_t)(((ibase + t3) * 16 + lo) * 16 + hi * 4) * 8);
#pragma unroll
            for (int q = 0; q < 8; q++) wreg[t3][q] = wp[q];
        }
        for (int bbi = 0; bbi < BCH; bbi++) {
            const int bb = (bbi + w * 4) & (BCH - 1);   // stagger waves
            const int b = b0 + bb;
            float sacc[4] = {0.f, 0.f, 0.f, 0.f};
#pragma unroll
            for (int t3 = 0; t3 < TPW; t3++) {
                const f4* xp = (const f4*)(x + ((size_t)b * N_IN + ibase + t3) * 8);
                f4 xa = xp[0], xb = xp[1];
#pragma unroll
                for (int t = 0; t < 4; t++) {
                    float a = 0.f;
#pragma unroll
                    for (int k = 0; k < 4; k++) a = fmaf(wreg[t3][2 * t][k], xa[k], a);
#pragma unroll
                    for (int k = 0; k < 4; k++) a = fmaf(wreg[t3][2 * t + 1][k], xb[k], a);
                    sacc[t] += a;
                }
            }
#pragma unroll
            for (int t = 0; t < 4; t++)
                atomicAdd(&sblk[bb * 256 + t * 64 + lane], sacc[t] * 0.0625f);
        }
    }
    __syncthreads();
#pragma unroll
    for (int r = 0; r < BCH; r++)
        Spart[((size_t)c * N_B + b0 + r) * 256 + tid] = sblk[r * 256 + tid];
}

// ---------------------------------------------------------------------------
// iter >= 1: u_hat recompute (fp32), logits via split-f16 MFMA vs Vsum,
// softmax over o per column, accumulate c*u (round-1-verified MFMA math).
// ---------------------------------------------------------------------------
__global__ __launch_bounds__(256, 3) void k_route(const float* __restrict__ x,
                                                  const float* __restrict__ W,
                                                  const float* __restrict__ Vsum,
                                                  float* __restrict__ Spart) {
    __shared__ float sblk[BCH * 256];
    const int c = blockIdx.x, spl = blockIdx.y;
    const int b0 = spl * BCH;
    const int tid = threadIdx.x, w = tid >> 6, lane = tid & 63;
    const int lo = lane & 15, hi = lane >> 4;

#pragma unroll
    for (int r = 0; r < BCH; r++) sblk[r * 256 + tid] = 0.f;
    __syncthreads();

    // identity B-fragment (U -> D-layout transpose MFMA)
    h4 idf;
#pragma unroll
    for (int t = 0; t < 4; t++) idf[t] = (_Float16)((hi * 4 + t == lo) ? 1.f : 0.f);

    for (int stg = 0; stg < NSTG; stg++) {
        const int ibase = c * ICH + stg * (TPW * 4) + w * TPW;
        f4 wreg[TPW][8];
#pragma unroll
        for (int t3 = 0; t3 < TPW; t3++) {
            const f4* wp = (const f4*)(W + (size_t)(((ibase + t3) * 16 + lo) * 16 + hi * 4) * 8);
#pragma unroll
            for (int q = 0; q < 8; q++) wreg[t3][q] = wp[q];
        }
        for (int bbi = 0; bbi < BCH; bbi++) {
            const int bb = (bbi + w * 4) & (BCH - 1);
            const int b = b0 + bb;
            // B-fragment of Vsum: lane (lo,hi) <- Vsum[b][lo*16 + hi*4 .. +3]
            f4 vv = *(const f4*)(Vsum + ((size_t)b * 256 + lo * 16 + hi * 4));
            h4 bh, bl;
#pragma unroll
            for (int t = 0; t < 4; t++) {
                _Float16 h = (_Float16)vv[t];
                bh[t] = h;
                bl[t] = (_Float16)(vv[t] - (float)h);
            }
            float sacc[4] = {0.f, 0.f, 0.f, 0.f};
#pragma unroll
            for (int t3 = 0; t3 < TPW; t3++) {
                const f4* xp = (const f4*)(x + ((size_t)b * N_IN + ibase + t3) * 8);
                f4 xa = xp[0], xb = xp[1];
                float u[4];
#pragma unroll
                for (int t = 0; t < 4; t++) {
                    float a = 0.f;
#pragma unroll
                    for (int k = 0; k < 4; k++) a = fmaf(wreg[t3][2 * t][k], xa[k], a);
#pragma unroll
                    for (int k = 0; k < 4; k++) a = fmaf(wreg[t3][2 * t + 1][k], xb[k], a);
                    u[t] = a;
                }
                h4 uh, ul;
#pragma unroll
                for (int t = 0; t < 4; t++) {
                    _Float16 h = (_Float16)u[t];
                    uh[t] = h;
                    ul[t] = (_Float16)(u[t] - (float)h);
                }
                f4 z = {0.f, 0.f, 0.f, 0.f};
                // logits L = U @ Vsum^T  (split f16 ~ fp32)
                f4 L = __builtin_amdgcn_mfma_f32_16x16x16f16(uh, bh, z, 0, 0, 0);
                L = __builtin_amdgcn_mfma_f32_16x16x16f16(ul, bh, L, 0, 0, 0);
                L = __builtin_amdgcn_mfma_f32_16x16x16f16(uh, bl, L, 0, 0, 0);
                // U transposed to D-layout via identity B
                f4 ud = __builtin_amdgcn_mfma_f32_16x16x16f16(uh, idf, z, 0, 0, 0);
                ud = __builtin_amdgcn_mfma_f32_16x16x16f16(ul, idf, ud, 0, 0, 0);
                // softmax over o (in-lane 4 + hi-groups via shfl 16,32)
                float p[4], zs = 0.f;
#pragma unroll
                for (int t = 0; t < 4; t++) { p[t] = __expf(L[t]); zs += p[t]; }
                zs += __shfl_xor(zs, 16);
                zs += __shfl_xor(zs, 32);
                float rin = __builtin_amdgcn_rcpf(zs);
#pragma unroll
                for (int t = 0; t < 4; t++) sacc[t] = fmaf(p[t] * rin, ud[t], sacc[t]);
            }
#pragma unroll
            for (int t = 0; t < 4; t++)
                atomicAdd(&sblk[bb * 256 + t * 64 + lane], sacc[t]);
        }
    }
    __syncthreads();
#pragma unroll
    for (int r = 0; r < BCH; r++)
        Spart[((size_t)c * N_B + b0 + r) * 256 + tid] = sblk[r * 256 + tid];
}

// ---------------------------------------------------------------------------
// Reduce 72 chunks (undoing the lane-major sblk permutation) + squash.
// MODE 0: Vsum = v (after iter0, A-layout source)
// MODE 1: Vsum += v (after iter1, D-layout source)
// MODE 2: out = v (final, D-layout source)
// ---------------------------------------------------------------------------
template <int MODE>
__global__ __launch_bounds__(256) void k_redsq(const float* __restrict__ Spart,
                                               float* __restrict__ Vsum,
                                               float* __restrict__ out) {
    const int b = blockIdx.x, tid = threadIdx.x;
    const int o = tid >> 4, d = tid & 15;
    const int q = (MODE == 0) ? ((d & 3) * 64 + (d >> 2) * 16 + o)
                              : ((o & 3) * 64 + (o >> 2) * 16 + d);
    float s = 0.f;
#pragma unroll 8
    for (int cc = 0; cc < NCH; cc++) s += Spart[((size_t)cc * N_B + b) * 256 + q];
    float sq = s * s;
    sq += __shfl_xor(sq, 1);
    sq += __shfl_xor(sq, 2);
    sq += __shfl_xor(sq, 4);
    sq += __shfl_xor(sq, 8);
    float scale = sq * __builtin_amdgcn_rcpf(1.f + sq);
    float v = s * scale * __builtin_amdgcn_rsqf(sq + 1e-8f);
    size_t idx = (size_t)b * 256 + tid;
    if (MODE == 0)      Vsum[idx] = v;
    else if (MODE == 1) Vsum[idx] += v;
    else                out[idx] = v;
}

// ---------------------------------------------------------------------------
extern "C" void kernel_launch(void* const* d_in, const int* in_sizes, int n_in,
                              void* d_out, int out_size, void* d_ws, size_t ws_size,
                              hipStream_t stream) {
    (void)in_sizes; (void)n_in; (void)out_size; (void)ws_size;
    const float* x = (const float*)d_in[0];
    const float* W = (const float*)d_in[1];
    float* out   = (float*)d_out;
    float* Spart = (float*)d_ws;
    float* Vsum  = (float*)((char*)d_ws + SPART_SZ);

    dim3 rg(NCH, BSPL);
    k_route0<<<rg, 256, 0, stream>>>(x, W, Spart);
    k_redsq<0><<<N_B, 256, 0, stream>>>(Spart, Vsum, out);
    k_route<<<rg, 256, 0, stream>>>(x, W, Vsum, Spart);
    k_redsq<1><<<N_B, 256, 0, stream>>>(Spart, Vsum, out);
    k_route<<<rg, 256, 0, stream>>>(x, W, Vsum, Spart);
    k_redsq<2><<<N_B, 256, 0, stream>>>(Spart, Vsum, out);
}